// Round 25
// baseline (84.228 us; speedup 1.0000x reference)
//
#include <hip/hip_runtime.h>
#include <hip/hip_bf16.h>

typedef __attribute__((ext_vector_type(8))) short bf16x8;
typedef __attribute__((ext_vector_type(4))) float f32x4;

#define NCOLP 384                 // padded columns (352 real + 32 zero)
#define STEP_SHORTS (NCOLP * 32)  // 12288 shorts = 24576 B per 32-k step
#define STEP_BYTES 24576
#define SEG_BYTES 6144            // Wpack per-ablk segment: 384 cols * 8k * 2B
#define NSTEP 32
#define BROWS 65536
#define QSZ 32768                 // quarter tile: 64 rows x 512 B bf16

static __device__ __forceinline__ unsigned int bf16rne(float f) {
  unsigned int u = __float_as_uint(f);
  return (u + 0x7FFFu + ((u >> 16) & 1u)) >> 16;
}
static __device__ __forceinline__ unsigned int pack2(float a, float b) {
  return bf16rne(a) | (bf16rne(b) << 16);
}

// Wpack layout: [step][ablk(4)][col(384)][k%8] (bf16), 24576 B/step.
// Column map: [0,100) task0 (e*10+h), [100,200) task1, [200,300) shared,
// [300,340) gates (t*20+g), [340,384) zero pad.
__global__ void ple_prep(const float* __restrict__ Ws, const float* __restrict__ bs,
                         const float* __restrict__ Wt, const float* __restrict__ bt,
                         const float* __restrict__ Wg, const float* __restrict__ bg,
                         unsigned short* __restrict__ Wpack, float* __restrict__ bias) {
  const int n = blockIdx.x;  // 0..383
  const int tid = threadIdx.x;
  const float* src = nullptr;
  int stride = 0;
  float bval = 0.f;
  if (n < 200) {
    int t = n / 100, m = n % 100, e = m / 10, h = m % 10;
    src = Wt + (size_t)(t * 10 + e) * 10240 + h;
    stride = 10;
    bval = bt[(t * 10 + e) * 10 + h];
  } else if (n < 300) {
    int m = n - 200, e = m / 10, h = m % 10;
    src = Ws + (size_t)e * 10240 + h;
    stride = 10;
    bval = bs[e * 10 + h];
  } else if (n < 340) {
    int m = n - 300, t = m / 20, g = m % 20;
    src = Wg + (size_t)t * 20480 + g;
    stride = 20;
    bval = bg[t * 20 + g];
  }
  for (int j = 0; j < 4; j++) {
    int k = tid + j * 256;
    float v = src ? src[(size_t)k * stride] : 0.f;
    Wpack[(size_t)(k >> 5) * STEP_SHORTS + ((k >> 3) & 3) * (NCOLP * 8) + n * 8 +
          (k & 7)] = (unsigned short)bf16rne(v);
  }
  if (tid == 0 && n < 352) bias[n] = bval;
}

// Main: 256 threads = 4 waves, 64 rows/block, 1024 blocks, 2 blocks/CU.
// R24 + DEEPENED A-PIPELINE: next quarter's first load-group is issued
// BEFORE the quarter barrier (register targets are private; lgkm-only
// barrier leaves them in flight) -> ~1500cy cover; the second group is
// issued after step 2 (write after step 7, ~1200cy). The HBM stream never
// drains: >=8 A-loads outstanding at every point incl. across barriers.
// Triple-banked lead-2 register B; one lgkm barrier per quarter.
__global__ __launch_bounds__(256, 2) void ple_main(
    const float* __restrict__ x, const unsigned short* __restrict__ Wpack,
    const float* __restrict__ bias, const float* __restrict__ Wc,
    const float* __restrict__ bc, const float* __restrict__ Wv,
    const float* __restrict__ bv, float* __restrict__ out) {
  __shared__ __align__(16) char smem[2 * QSZ];  // z[32][357] aliases front
  float* z = (float*)smem;

  const int tid = threadIdx.x;
  const int l = tid & 63, w = tid >> 6;  // wave w -> cols [w*96, w*96+96)
  const int arow = l & 15, ablk = l >> 4;
  const int rowbase = blockIdx.x * 64;

  const f32x4 fzero = {0.f, 0.f, 0.f, 0.f};
  f32x4 acc[4][6];
#pragma unroll
  for (int i = 0; i < 4; ++i)
#pragma unroll
    for (int j = 0; j < 6; ++j) acc[i][j] = fzero;

  // B fragment base (per-lane 16B from Wpack; k-order matches A frags).
  const char* bbase = (const char*)Wpack + ablk * SEG_BYTES +
                      (w * 96 + arow) * 16;
  bf16x8 b0[6], b1[6], b2[6];  // triple bank, static indexing only

  // Preload B steps 0,1.
#pragma unroll
  for (int nt = 0; nt < 6; nt++) {
    b0[nt] = *(const bf16x8*)(bbase + nt * 256);
    b1[nt] = *(const bf16x8*)(bbase + STEP_BYTES + nt * 256);
  }

  // A staging: wave w covers rows w+4j (j=0..15); lane l = 16B fp32 seg l
  // of the current quarter (64 lanes x 16B = 1KB/row/quarter, coalesced).
  const char* xstage = (const char*)x + (size_t)(rowbase + w) * 4096 + l * 16;
  float4 g[8], hgrp[8];

#define GISSUE(Q, G, J0)                                                       \
  {                                                                            \
    _Pragma("unroll") for (int j = 0; j < 8; j++)                              \
        G[j] = *(const float4*)(xstage + (size_t)((J0) + j) * 4 * 4096 +       \
                                (Q)*1024);                                     \
  }
#define GWRITE(Q, G, J0)                                                       \
  {                                                                            \
    _Pragma("unroll") for (int j = 0; j < 8; j++) {                            \
      const int row = w + ((J0) + j) * 4;                                      \
      const int s = l >> 1;                                                    \
      const int segp = (s & 24) | ((s & 7) ^ (row & 7));                       \
      uint2 u;                                                                 \
      u.x = pack2(G[j].x, G[j].y);                                             \
      u.y = pack2(G[j].z, G[j].w);                                             \
      *(uint2*)(smem + ((Q)&1) * QSZ + row * 512 + segp * 16 + (l & 1) * 8) =  \
          u;                                                                   \
    }                                                                          \
  }
  // STEPX(I, BU, BP): consume bank BU (= step I), prefetch step I+2 -> BP.
  // Reads A from buf[(I>>3)&1], quarter-local seg s = (I&7)*4+ablk.
#define STEPX(I, BU, BP)                                                       \
  {                                                                            \
    const int ipre = ((I) + 2 <= 31) ? (I) + 2 : 31;                           \
    const char* bp = bbase + (size_t)ipre * STEP_BYTES;                        \
    _Pragma("unroll") for (int nt = 0; nt < 6; nt++)                           \
        BP[nt] = *(const bf16x8*)(bp + nt * 256);                              \
    _Pragma("unroll") for (int mf = 0; mf < 4; mf++) {                         \
      const int s = ((I)&7) * 4 + ablk;                                        \
      const int segp = (s & 24) | ((s & 7) ^ (arow & 7));                      \
      const bf16x8 av =                                                        \
          *(const bf16x8*)(smem + (((I) >> 3) & 1) * QSZ +                     \
                           (mf * 16 + arow) * 512 + segp * 16);                \
      _Pragma("unroll") for (int nt = 0; nt < 6; nt++)                         \
          acc[mf][nt] = __builtin_amdgcn_mfma_f32_16x16x32_bf16(               \
              av, BU[nt], acc[mf][nt], 0, 0, 0);                               \
    }                                                                          \
  }
#define SB __builtin_amdgcn_sched_barrier(0);
#define QBAR                                                                   \
  asm volatile("s_waitcnt lgkmcnt(0)" ::: "memory");                           \
  __builtin_amdgcn_s_barrier();

  // ---- prologue: stage quarter 0 -> buf0; issue quarter1 group g ----
  GISSUE(0, g, 0) SB GWRITE(0, g, 0) SB GISSUE(0, hgrp, 8) SB
  GWRITE(0, hgrp, 8) SB GISSUE(1, g, 0) QBAR SB

  // ---- Q0: compute buf0 (0-7); stage q1 -> buf1; issue q2.g at end ----
  STEPX(0, b0, b2) STEPX(1, b1, b0) STEPX(2, b2, b1)
  SB GISSUE(1, hgrp, 8) SB
  STEPX(3, b0, b2) STEPX(4, b1, b0)
  SB GWRITE(1, g, 0) SB
  STEPX(5, b2, b1) STEPX(6, b0, b2)
  SB GWRITE(1, hgrp, 8) SB
  STEPX(7, b1, b0)
  SB GISSUE(2, g, 0) QBAR SB

  // ---- Q1: compute buf1 (8-15); stage q2 -> buf0; issue q3.g ----
  STEPX(8, b2, b1) STEPX(9, b0, b2) STEPX(10, b1, b0)
  SB GISSUE(2, hgrp, 8) SB
  STEPX(11, b2, b1) STEPX(12, b0, b2)
  SB GWRITE(2, g, 0) SB
  STEPX(13, b1, b0) STEPX(14, b2, b1)
  SB GWRITE(2, hgrp, 8) SB
  STEPX(15, b0, b2)
  SB GISSUE(3, g, 0) QBAR SB

  // ---- Q2: compute buf0 (16-23); stage q3 -> buf1 ----
  STEPX(16, b1, b0) STEPX(17, b2, b1) STEPX(18, b0, b2)
  SB GISSUE(3, hgrp, 8) SB
  STEPX(19, b1, b0) STEPX(20, b2, b1)
  SB GWRITE(3, g, 0) SB
  STEPX(21, b0, b2) STEPX(22, b1, b0)
  SB GWRITE(3, hgrp, 8) SB
  STEPX(23, b2, b1)
  QBAR SB

  // ---- Q3: compute buf1 (24-31), no staging ----
  STEPX(24, b0, b2) STEPX(25, b1, b0) STEPX(26, b2, b1) STEPX(27, b0, b2)
  STEPX(28, b1, b0) STEPX(29, b2, b1) STEPX(30, b0, b2) STEPX(31, b1, b0)
  QBAR

#undef QBAR
#undef SB
#undef STEPX
#undef GWRITE
#undef GISSUE

  // ---- epilogue: 2 phases of 32 rows; 4 threads per (task,row) item.
  // D layout: row=(l>>4)*4+reg, col=l&15.
#pragma unroll
  for (int p = 0; p < 2; p++) {
    __syncthreads();
#pragma unroll
    for (int q = 0; q < 2; q++) {
      const int mf = p * 2 + q;
#pragma unroll
      for (int nt = 0; nt < 6; nt++) {
        if (w == 3 && nt >= 4) continue;  // cols >= 352 are zero pad
#pragma unroll
        for (int r = 0; r < 4; r++)
          z[(q * 16 + ablk * 4 + r) * 357 + w * 96 + nt * 16 + arow] =
              acc[mf][nt][r];
      }
    }
    __syncthreads();
    {
      const int item = tid >> 2, sub = tid & 3;  // 64 items x 4 threads
      const int t = item >> 5, r = item & 31;
      const float* zr = &z[r * 357];
      float gl[5], m = -1e30f;
#pragma unroll
      for (int v = 0; v < 5; v++) {
        const int u = sub * 5 + v;
        gl[v] = zr[300 + t * 20 + u] + bias[300 + t * 20 + u];
        m = fmaxf(m, gl[v]);
      }
      m = fmaxf(m, __shfl_xor(m, 1));
      m = fmaxf(m, __shfl_xor(m, 2));
      const float* Wl = t ? Wv : Wc;
      float wl[10];
#pragma unroll
      for (int h = 0; h < 10; h++) wl[h] = Wl[h];
      float s = 0.f, accum = 0.f;
#pragma unroll
      for (int v = 0; v < 5; v++) {
        const int u = sub * 5 + v;
        const float pu = __expf(gl[v] - m);
        s += pu;
        const int cbase = (u < 10) ? (t * 100 + u * 10) : (200 + (u - 10) * 10);
        float d = 0.f;
#pragma unroll
        for (int h = 0; h < 10; h++)
          d += fmaxf(zr[cbase + h] + bias[cbase + h], 0.f) * wl[h];
        accum += pu * d;
      }
      s += __shfl_xor(s, 1);
      s += __shfl_xor(s, 2);
      accum += __shfl_xor(accum, 1);
      accum += __shfl_xor(accum, 2);
      if (sub == 0) {
        const float logit = (t ? bv[0] : bc[0]) + accum / s;
        out[(size_t)t * BROWS + rowbase + p * 32 + r] =
            1.f / (1.f + __expf(-logit));
      }
    }
  }
}

extern "C" void kernel_launch(void* const* d_in, const int* in_sizes, int n_in,
                              void* d_out, int out_size, void* d_ws, size_t ws_size,
                              hipStream_t stream) {
  const float* x = (const float*)d_in[0];
  const float* Ws = (const float*)d_in[3];
  const float* bs = (const float*)d_in[4];
  const float* Wt = (const float*)d_in[5];
  const float* bt = (const float*)d_in[6];
  const float* Wg = (const float*)d_in[7];
  const float* bg = (const float*)d_in[8];
  const float* Wc = (const float*)d_in[9];
  const float* bc = (const float*)d_in[10];
  const float* Wv = (const float*)d_in[11];
  const float* bv = (const float*)d_in[12];
  unsigned short* Wpack = (unsigned short*)d_ws;
  float* bias = (float*)((char*)d_ws + (size_t)NCOLP * 1024 * 2);
  float* out = (float*)d_out;

  hipLaunchKernelGGL(ple_prep, dim3(NCOLP), dim3(256), 0, stream, Ws, bs, Wt, bt,
                     Wg, bg, Wpack, bias);
  hipLaunchKernelGGL(ple_main, dim3(BROWS / 64), dim3(256), 0, stream, x, Wpack,
                     bias, Wc, bc, Wv, bv, out);
}

// Round 26
// 78.459 us; speedup vs baseline: 1.0735x; 1.0735x over previous
//
#include <hip/hip_runtime.h>
#include <hip/hip_bf16.h>

typedef __attribute__((ext_vector_type(8))) short bf16x8;
typedef __attribute__((ext_vector_type(4))) float f32x4;

#define NCOLP 384                 // padded columns (352 real + 32 zero)
#define STEP_SHORTS (NCOLP * 32)  // 12288 shorts = 24576 B per 32-k step
#define STEP_BYTES 24576
#define SEG_BYTES 6144            // Wpack per-ablk segment: 384 cols * 8k * 2B
#define NSTEP 32
#define BROWS 65536
#define QSZ 32768                 // quarter tile: 64 rows x 512 B bf16

static __device__ __forceinline__ unsigned int bf16rne(float f) {
  unsigned int u = __float_as_uint(f);
  return (u + 0x7FFFu + ((u >> 16) & 1u)) >> 16;
}
static __device__ __forceinline__ unsigned int pack2(float a, float b) {
  return bf16rne(a) | (bf16rne(b) << 16);
}

// Wpack layout: [step][ablk(4)][col(384)][k%8] (bf16), 24576 B/step.
// Column map: [0,100) task0 (e*10+h), [100,200) task1, [200,300) shared,
// [300,340) gates (t*20+g), [340,384) zero pad.
__global__ void ple_prep(const float* __restrict__ Ws, const float* __restrict__ bs,
                         const float* __restrict__ Wt, const float* __restrict__ bt,
                         const float* __restrict__ Wg, const float* __restrict__ bg,
                         unsigned short* __restrict__ Wpack, float* __restrict__ bias) {
  const int n = blockIdx.x;  // 0..383
  const int tid = threadIdx.x;
  const float* src = nullptr;
  int stride = 0;
  float bval = 0.f;
  if (n < 200) {
    int t = n / 100, m = n % 100, e = m / 10, h = m % 10;
    src = Wt + (size_t)(t * 10 + e) * 10240 + h;
    stride = 10;
    bval = bt[(t * 10 + e) * 10 + h];
  } else if (n < 300) {
    int m = n - 200, e = m / 10, h = m % 10;
    src = Ws + (size_t)e * 10240 + h;
    stride = 10;
    bval = bs[e * 10 + h];
  } else if (n < 340) {
    int m = n - 300, t = m / 20, g = m % 20;
    src = Wg + (size_t)t * 20480 + g;
    stride = 20;
    bval = bg[t * 20 + g];
  }
  for (int j = 0; j < 4; j++) {
    int k = tid + j * 256;
    float v = src ? src[(size_t)k * stride] : 0.f;
    Wpack[(size_t)(k >> 5) * STEP_SHORTS + ((k >> 3) & 3) * (NCOLP * 8) + n * 8 +
          (k & 7)] = (unsigned short)bf16rne(v);
  }
  if (tid == 0 && n < 352) bias[n] = bval;
}

// Main: 256 threads = 4 waves, 64 rows/block, 1024 blocks, 2 blocks/CU.
// R24 (in-compute staging, double-buffered quarters, triple-banked lead-2
// register B) + QUARTER-SEQUENCE STAGGER: odd blocks process physical
// quarters {2,3,0,1}, even {0,1,2,3} (K-sum commutes). The two resident
// blocks' HBM stage bursts anti-correlate, filling each other's
// pack-wait windows. Indexing is by processed position I: global step
// kk = (h0*16 + I) & 31; quarter-local seg = I&7; LDS buffer parity by
// position; B prefetch wraps continuously.
__global__ __launch_bounds__(256, 2) void ple_main(
    const float* __restrict__ x, const unsigned short* __restrict__ Wpack,
    const float* __restrict__ bias, const float* __restrict__ Wc,
    const float* __restrict__ bc, const float* __restrict__ Wv,
    const float* __restrict__ bv, float* __restrict__ out) {
  __shared__ __align__(16) char smem[2 * QSZ];  // z[32][357] aliases front
  float* z = (float*)smem;

  const int tid = threadIdx.x;
  const int l = tid & 63, w = tid >> 6;  // wave w -> cols [w*96, w*96+96)
  const int arow = l & 15, ablk = l >> 4;
  const int rowbase = blockIdx.x * 64;
  const int h0 = (int)(blockIdx.x & 1);  // stagger: start at quarter h0*2

  const f32x4 fzero = {0.f, 0.f, 0.f, 0.f};
  f32x4 acc[4][6];
#pragma unroll
  for (int i = 0; i < 4; ++i)
#pragma unroll
    for (int j = 0; j < 6; ++j) acc[i][j] = fzero;

  // B fragment base (per-lane 16B from Wpack; k-order matches A frags).
  const char* bbase = (const char*)Wpack + ablk * SEG_BYTES +
                      (w * 96 + arow) * 16;
  bf16x8 b0[6], b1[6], b2[6];  // triple bank, static indexing only

  // Preload B for processed positions 0,1 (global steps (h0*16+{0,1})&31).
#pragma unroll
  for (int nt = 0; nt < 6; nt++) {
    b0[nt] = *(const bf16x8*)(bbase + (size_t)((h0 << 4) & 31) * STEP_BYTES +
                              nt * 256);
    b1[nt] = *(const bf16x8*)(bbase +
                              (size_t)(((h0 << 4) + 1) & 31) * STEP_BYTES +
                              nt * 256);
  }

  // A staging: wave w covers rows w+4j (j=0..15); lane l = 16B fp32 seg l
  // of the staged quarter (64 lanes x 16B = 1KB/row/quarter, coalesced).
  const char* xstage = (const char*)x + (size_t)(rowbase + w) * 4096 + l * 16;
  float4 g[8], hgrp[8];

  // P = processed quarter position (0..3); physical quarter = (h0*2+P)&3.
#define GISSUE(P, G, J0)                                                       \
  {                                                                            \
    const int qp = ((h0 << 1) + (P)) & 3;                                      \
    _Pragma("unroll") for (int j = 0; j < 8; j++)                              \
        G[j] = *(const float4*)(xstage + (size_t)((J0) + j) * 4 * 4096 +       \
                                qp * 1024);                                    \
  }
#define GWRITE(P, G, J0)                                                       \
  {                                                                            \
    _Pragma("unroll") for (int j = 0; j < 8; j++) {                            \
      const int row = w + ((J0) + j) * 4;                                      \
      const int s = l >> 1;                                                    \
      const int segp = (s & 24) | ((s & 7) ^ (row & 7));                       \
      uint2 u;                                                                 \
      u.x = pack2(G[j].x, G[j].y);                                             \
      u.y = pack2(G[j].z, G[j].w);                                             \
      *(uint2*)(smem + ((P)&1) * QSZ + row * 512 + segp * 16 + (l & 1) * 8) =  \
          u;                                                                   \
    }                                                                          \
  }
  // STEPX(I, BU, BP): consume bank BU (= position I, step (h0*16+I)&31),
  // prefetch position I+2 -> BP. A from buf[(I>>3)&1], seg s=(I&7)*4+ablk.
#define STEPX(I, BU, BP)                                                       \
  {                                                                            \
    const int ipre = ((I) + 2 <= 31) ? (I) + 2 : 31;                           \
    const int kpre = ((h0 << 4) + ipre) & 31;                                  \
    const char* bp = bbase + (size_t)kpre * STEP_BYTES;                        \
    _Pragma("unroll") for (int nt = 0; nt < 6; nt++)                           \
        BP[nt] = *(const bf16x8*)(bp + nt * 256);                              \
    _Pragma("unroll") for (int mf = 0; mf < 4; mf++) {                         \
      const int s = ((I)&7) * 4 + ablk;                                        \
      const int segp = (s & 24) | ((s & 7) ^ (arow & 7));                      \
      const bf16x8 av =                                                        \
          *(const bf16x8*)(smem + (((I) >> 3) & 1) * QSZ +                     \
                           (mf * 16 + arow) * 512 + segp * 16);                \
      _Pragma("unroll") for (int nt = 0; nt < 6; nt++)                         \
          acc[mf][nt] = __builtin_amdgcn_mfma_f32_16x16x32_bf16(               \
              av, BU[nt], acc[mf][nt], 0, 0, 0);                               \
    }                                                                          \
  }
#define SB __builtin_amdgcn_sched_barrier(0);
#define QBAR                                                                   \
  asm volatile("s_waitcnt lgkmcnt(0)" ::: "memory");                           \
  __builtin_amdgcn_s_barrier();

  // ---- prologue: stage position 0 -> buf0 (depth-8 groups) ----
  GISSUE(0, g, 0) SB GWRITE(0, g, 0) SB GISSUE(0, hgrp, 8) SB
  GWRITE(0, hgrp, 8) QBAR SB

  // ---- P0: compute buf0 (positions 0-7), stage position1 -> buf1 ----
  STEPX(0, b0, b2) STEPX(1, b1, b0)
  SB GISSUE(1, g, 0) SB
  STEPX(2, b2, b1) STEPX(3, b0, b2) STEPX(4, b1, b0)
  SB GWRITE(1, g, 0) SB GISSUE(1, hgrp, 8) SB
  STEPX(5, b2, b1) STEPX(6, b0, b2) STEPX(7, b1, b0)
  SB GWRITE(1, hgrp, 8) QBAR SB

  // ---- P1: compute buf1 (positions 8-15), stage position2 -> buf0 ----
  STEPX(8, b2, b1) STEPX(9, b0, b2)
  SB GISSUE(2, g, 0) SB
  STEPX(10, b1, b0) STEPX(11, b2, b1) STEPX(12, b0, b2)
  SB GWRITE(2, g, 0) SB GISSUE(2, hgrp, 8) SB
  STEPX(13, b1, b0) STEPX(14, b2, b1) STEPX(15, b0, b2)
  SB GWRITE(2, hgrp, 8) QBAR SB

  // ---- P2: compute buf0 (positions 16-23), stage position3 -> buf1 ----
  STEPX(16, b1, b0) STEPX(17, b2, b1)
  SB GISSUE(3, g, 0) SB
  STEPX(18, b0, b2) STEPX(19, b1, b0) STEPX(20, b2, b1)
  SB GWRITE(3, g, 0) SB GISSUE(3, hgrp, 8) SB
  STEPX(21, b0, b2) STEPX(22, b1, b0) STEPX(23, b2, b1)
  SB GWRITE(3, hgrp, 8) QBAR SB

  // ---- P3: compute buf1 (positions 24-31), no staging ----
  STEPX(24, b0, b2) STEPX(25, b1, b0) STEPX(26, b2, b1) STEPX(27, b0, b2)
  STEPX(28, b1, b0) STEPX(29, b2, b1) STEPX(30, b0, b2) STEPX(31, b1, b0)
  QBAR

#undef QBAR
#undef SB
#undef STEPX
#undef GWRITE
#undef GISSUE

  // ---- epilogue: 2 phases of 32 rows; 4 threads per (task,row) item.
  // D layout: row=(l>>4)*4+reg, col=l&15.
#pragma unroll
  for (int p = 0; p < 2; p++) {
    __syncthreads();
#pragma unroll
    for (int q = 0; q < 2; q++) {
      const int mf = p * 2 + q;
#pragma unroll
      for (int nt = 0; nt < 6; nt++) {
        if (w == 3 && nt >= 4) continue;  // cols >= 352 are zero pad
#pragma unroll
        for (int r = 0; r < 4; r++)
          z[(q * 16 + ablk * 4 + r) * 357 + w * 96 + nt * 16 + arow] =
              acc[mf][nt][r];
      }
    }
    __syncthreads();
    {
      const int item = tid >> 2, sub = tid & 3;  // 64 items x 4 threads
      const int t = item >> 5, r = item & 31;
      const float* zr = &z[r * 357];
      float gl[5], m = -1e30f;
#pragma unroll
      for (int v = 0; v < 5; v++) {
        const int u = sub * 5 + v;
        gl[v] = zr[300 + t * 20 + u] + bias[300 + t * 20 + u];
        m = fmaxf(m, gl[v]);
      }
      m = fmaxf(m, __shfl_xor(m, 1));
      m = fmaxf(m, __shfl_xor(m, 2));
      const float* Wl = t ? Wv : Wc;
      float wl[10];
#pragma unroll
      for (int h = 0; h < 10; h++) wl[h] = Wl[h];
      float s = 0.f, accum = 0.f;
#pragma unroll
      for (int v = 0; v < 5; v++) {
        const int u = sub * 5 + v;
        const float pu = __expf(gl[v] - m);
        s += pu;
        const int cbase = (u < 10) ? (t * 100 + u * 10) : (200 + (u - 10) * 10);
        float d = 0.f;
#pragma unroll
        for (int h = 0; h < 10; h++)
          d += fmaxf(zr[cbase + h] + bias[cbase + h], 0.f) * wl[h];
        accum += pu * d;
      }
      s += __shfl_xor(s, 1);
      s += __shfl_xor(s, 2);
      accum += __shfl_xor(accum, 1);
      accum += __shfl_xor(accum, 2);
      if (sub == 0) {
        const float logit = (t ? bv[0] : bc[0]) + accum / s;
        out[(size_t)t * BROWS + rowbase + p * 32 + r] =
            1.f / (1.f + __expf(-logit));
      }
    }
  }
}

extern "C" void kernel_launch(void* const* d_in, const int* in_sizes, int n_in,
                              void* d_out, int out_size, void* d_ws, size_t ws_size,
                              hipStream_t stream) {
  const float* x = (const float*)d_in[0];
  const float* Ws = (const float*)d_in[3];
  const float* bs = (const float*)d_in[4];
  const float* Wt = (const float*)d_in[5];
  const float* bt = (const float*)d_in[6];
  const float* Wg = (const float*)d_in[7];
  const float* bg = (const float*)d_in[8];
  const float* Wc = (const float*)d_in[9];
  const float* bc = (const float*)d_in[10];
  const float* Wv = (const float*)d_in[11];
  const float* bv = (const float*)d_in[12];
  unsigned short* Wpack = (unsigned short*)d_ws;
  float* bias = (float*)((char*)d_ws + (size_t)NCOLP * 1024 * 2);
  float* out = (float*)d_out;

  hipLaunchKernelGGL(ple_prep, dim3(NCOLP), dim3(256), 0, stream, Ws, bs, Wt, bt,
                     Wg, bg, Wpack, bias);
  hipLaunchKernelGGL(ple_main, dim3(BROWS / 64), dim3(256), 0, stream, x, Wpack,
                     bias, Wc, bc, Wv, bv, out);
}

// Round 27
// 77.823 us; speedup vs baseline: 1.0823x; 1.0082x over previous
//
#include <hip/hip_runtime.h>
#include <hip/hip_bf16.h>

typedef __attribute__((ext_vector_type(8))) short bf16x8;
typedef __attribute__((ext_vector_type(4))) float f32x4;

#define NCOLP 384                 // padded columns (352 real + 32 zero)
#define STEP_SHORTS (NCOLP * 32)  // 12288 shorts = 24576 B per 32-k step
#define STEP_BYTES 24576
#define SEG_BYTES 6144            // Wpack per-ablk segment: 384 cols * 8k * 2B
#define NSTEP 32
#define BROWS 65536
#define QSZ 32768                 // quarter tile: 64 rows x 512 B bf16

static __device__ __forceinline__ unsigned int bf16rne(float f) {
  unsigned int u = __float_as_uint(f);
  return (u + 0x7FFFu + ((u >> 16) & 1u)) >> 16;
}
static __device__ __forceinline__ unsigned int pack2(float a, float b) {
  return bf16rne(a) | (bf16rne(b) << 16);
}

// Wpack layout: [step][ablk(4)][col(384)][k%8] (bf16), 24576 B/step.
// Column map: [0,100) task0 (e*10+h), [100,200) task1, [200,300) shared,
// [300,340) gates (t*20+g), [340,384) zero pad.
__global__ void ple_prep(const float* __restrict__ Ws, const float* __restrict__ bs,
                         const float* __restrict__ Wt, const float* __restrict__ bt,
                         const float* __restrict__ Wg, const float* __restrict__ bg,
                         unsigned short* __restrict__ Wpack, float* __restrict__ bias) {
  const int n = blockIdx.x;  // 0..383
  const int tid = threadIdx.x;
  const float* src = nullptr;
  int stride = 0;
  float bval = 0.f;
  if (n < 200) {
    int t = n / 100, m = n % 100, e = m / 10, h = m % 10;
    src = Wt + (size_t)(t * 10 + e) * 10240 + h;
    stride = 10;
    bval = bt[(t * 10 + e) * 10 + h];
  } else if (n < 300) {
    int m = n - 200, e = m / 10, h = m % 10;
    src = Ws + (size_t)e * 10240 + h;
    stride = 10;
    bval = bs[e * 10 + h];
  } else if (n < 340) {
    int m = n - 300, t = m / 20, g = m % 20;
    src = Wg + (size_t)t * 20480 + g;
    stride = 20;
    bval = bg[t * 20 + g];
  }
  for (int j = 0; j < 4; j++) {
    int k = tid + j * 256;
    float v = src ? src[(size_t)k * stride] : 0.f;
    Wpack[(size_t)(k >> 5) * STEP_SHORTS + ((k >> 3) & 3) * (NCOLP * 8) + n * 8 +
          (k & 7)] = (unsigned short)bf16rne(v);
  }
  if (tid == 0 && n < 352) bias[n] = bval;
}

// Main: 256 threads = 4 waves, 64 rows/block, 1024 blocks, 2 blocks/CU.
// R26 chassis (in-compute staging, double-buffered quarters, triple-bank
// lead-2 register B) + 4-WAY QUARTER STAGGER (q0 = blockIdx&3; K-sum
// commutes) for device-wide HBM stage decorrelation, and B preload
// hoisted BEFORE the prologue stage so its L2 latency hides under the
// 16-deep HBM burst. All indexing by processed position I: global step
// kk = (q0*8 + I) & 31; physical quarter = (q0 + P) & 3.
__global__ __launch_bounds__(256, 2) void ple_main(
    const float* __restrict__ x, const unsigned short* __restrict__ Wpack,
    const float* __restrict__ bias, const float* __restrict__ Wc,
    const float* __restrict__ bc, const float* __restrict__ Wv,
    const float* __restrict__ bv, float* __restrict__ out) {
  __shared__ __align__(16) char smem[2 * QSZ];  // z[32][357] aliases front
  float* z = (float*)smem;

  const int tid = threadIdx.x;
  const int l = tid & 63, w = tid >> 6;  // wave w -> cols [w*96, w*96+96)
  const int arow = l & 15, ablk = l >> 4;
  const int rowbase = blockIdx.x * 64;
  const int q0 = (int)(blockIdx.x & 3);  // 4-way stagger start quarter

  const f32x4 fzero = {0.f, 0.f, 0.f, 0.f};
  f32x4 acc[4][6];
#pragma unroll
  for (int i = 0; i < 4; ++i)
#pragma unroll
    for (int j = 0; j < 6; ++j) acc[i][j] = fzero;

  // B fragment base (per-lane 16B from Wpack; k-order matches A frags).
  const char* bbase = (const char*)Wpack + ablk * SEG_BYTES +
                      (w * 96 + arow) * 16;
  bf16x8 b0[6], b1[6], b2[6];  // triple bank, static indexing only

  // A staging: wave w covers rows w+4j (j=0..15); lane l = 16B fp32 seg l
  // of the staged quarter (64 lanes x 16B = 1KB/row/quarter, coalesced).
  const char* xstage = (const char*)x + (size_t)(rowbase + w) * 4096 + l * 16;
  float4 g[8], hgrp[8];

  // P = processed quarter position (0..3); physical quarter = (q0+P)&3.
#define GISSUE(P, G, J0)                                                       \
  {                                                                            \
    const int qp = (q0 + (P)) & 3;                                             \
    _Pragma("unroll") for (int j = 0; j < 8; j++)                              \
        G[j] = *(const float4*)(xstage + (size_t)((J0) + j) * 4 * 4096 +       \
                                qp * 1024);                                    \
  }
#define GWRITE(P, G, J0)                                                       \
  {                                                                            \
    _Pragma("unroll") for (int j = 0; j < 8; j++) {                            \
      const int row = w + ((J0) + j) * 4;                                      \
      const int s = l >> 1;                                                    \
      const int segp = (s & 24) | ((s & 7) ^ (row & 7));                       \
      uint2 u;                                                                 \
      u.x = pack2(G[j].x, G[j].y);                                             \
      u.y = pack2(G[j].z, G[j].w);                                             \
      *(uint2*)(smem + ((P)&1) * QSZ + row * 512 + segp * 16 + (l & 1) * 8) =  \
          u;                                                                   \
    }                                                                          \
  }
  // STEPX(I, BU, BP): consume bank BU (= position I, step (q0*8+I)&31),
  // prefetch position I+2 -> BP. A from buf[(I>>3)&1], seg s=(I&7)*4+ablk.
#define STEPX(I, BU, BP)                                                       \
  {                                                                            \
    const int ipre = ((I) + 2 <= 31) ? (I) + 2 : 31;                           \
    const int kpre = (q0 * 8 + ipre) & 31;                                     \
    const char* bp = bbase + (size_t)kpre * STEP_BYTES;                        \
    _Pragma("unroll") for (int nt = 0; nt < 6; nt++)                           \
        BP[nt] = *(const bf16x8*)(bp + nt * 256);                              \
    _Pragma("unroll") for (int mf = 0; mf < 4; mf++) {                         \
      const int s = ((I)&7) * 4 + ablk;                                        \
      const int segp = (s & 24) | ((s & 7) ^ (arow & 7));                      \
      const bf16x8 av =                                                        \
          *(const bf16x8*)(smem + (((I) >> 3) & 1) * QSZ +                     \
                           (mf * 16 + arow) * 512 + segp * 16);                \
      _Pragma("unroll") for (int nt = 0; nt < 6; nt++)                         \
          acc[mf][nt] = __builtin_amdgcn_mfma_f32_16x16x32_bf16(               \
              av, BU[nt], acc[mf][nt], 0, 0, 0);                               \
    }                                                                          \
  }
#define SB __builtin_amdgcn_sched_barrier(0);
#define QBAR                                                                   \
  asm volatile("s_waitcnt lgkmcnt(0)" ::: "memory");                           \
  __builtin_amdgcn_s_barrier();

  // ---- prologue: B preload (positions 0,1) issued FIRST, then stage
  // position 0 -> buf0 (depth-8 groups); B latency hides under the burst.
#pragma unroll
  for (int nt = 0; nt < 6; nt++) {
    b0[nt] = *(const bf16x8*)(bbase + (size_t)((q0 * 8) & 31) * STEP_BYTES +
                              nt * 256);
    b1[nt] = *(const bf16x8*)(bbase +
                              (size_t)((q0 * 8 + 1) & 31) * STEP_BYTES +
                              nt * 256);
  }
  SB
  GISSUE(0, g, 0) SB GWRITE(0, g, 0) SB GISSUE(0, hgrp, 8) SB
  GWRITE(0, hgrp, 8) QBAR SB

  // ---- P0: compute buf0 (positions 0-7), stage position1 -> buf1 ----
  STEPX(0, b0, b2) STEPX(1, b1, b0)
  SB GISSUE(1, g, 0) SB
  STEPX(2, b2, b1) STEPX(3, b0, b2) STEPX(4, b1, b0)
  SB GWRITE(1, g, 0) SB GISSUE(1, hgrp, 8) SB
  STEPX(5, b2, b1) STEPX(6, b0, b2) STEPX(7, b1, b0)
  SB GWRITE(1, hgrp, 8) QBAR SB

  // ---- P1: compute buf1 (positions 8-15), stage position2 -> buf0 ----
  STEPX(8, b2, b1) STEPX(9, b0, b2)
  SB GISSUE(2, g, 0) SB
  STEPX(10, b1, b0) STEPX(11, b2, b1) STEPX(12, b0, b2)
  SB GWRITE(2, g, 0) SB GISSUE(2, hgrp, 8) SB
  STEPX(13, b1, b0) STEPX(14, b2, b1) STEPX(15, b0, b2)
  SB GWRITE(2, hgrp, 8) QBAR SB

  // ---- P2: compute buf0 (positions 16-23), stage position3 -> buf1 ----
  STEPX(16, b1, b0) STEPX(17, b2, b1)
  SB GISSUE(3, g, 0) SB
  STEPX(18, b0, b2) STEPX(19, b1, b0) STEPX(20, b2, b1)
  SB GWRITE(3, g, 0) SB GISSUE(3, hgrp, 8) SB
  STEPX(21, b0, b2) STEPX(22, b1, b0) STEPX(23, b2, b1)
  SB GWRITE(3, hgrp, 8) QBAR SB

  // ---- P3: compute buf1 (positions 24-31), no staging ----
  STEPX(24, b0, b2) STEPX(25, b1, b0) STEPX(26, b2, b1) STEPX(27, b0, b2)
  STEPX(28, b1, b0) STEPX(29, b2, b1) STEPX(30, b0, b2) STEPX(31, b1, b0)
  QBAR

#undef QBAR
#undef SB
#undef STEPX
#undef GWRITE
#undef GISSUE

  // ---- epilogue: 2 phases of 32 rows; 4 threads per (task,row) item.
  // D layout: row=(l>>4)*4+reg, col=l&15.
#pragma unroll
  for (int p = 0; p < 2; p++) {
    __syncthreads();
#pragma unroll
    for (int q = 0; q < 2; q++) {
      const int mf = p * 2 + q;
#pragma unroll
      for (int nt = 0; nt < 6; nt++) {
        if (w == 3 && nt >= 4) continue;  // cols >= 352 are zero pad
#pragma unroll
        for (int r = 0; r < 4; r++)
          z[(q * 16 + ablk * 4 + r) * 357 + w * 96 + nt * 16 + arow] =
              acc[mf][nt][r];
      }
    }
    __syncthreads();
    {
      const int item = tid >> 2, sub = tid & 3;  // 64 items x 4 threads
      const int t = item >> 5, r = item & 31;
      const float* zr = &z[r * 357];
      float gl[5], m = -1e30f;
#pragma unroll
      for (int v = 0; v < 5; v++) {
        const int u = sub * 5 + v;
        gl[v] = zr[300 + t * 20 + u] + bias[300 + t * 20 + u];
        m = fmaxf(m, gl[v]);
      }
      m = fmaxf(m, __shfl_xor(m, 1));
      m = fmaxf(m, __shfl_xor(m, 2));
      const float* Wl = t ? Wv : Wc;
      float wl[10];
#pragma unroll
      for (int h = 0; h < 10; h++) wl[h] = Wl[h];
      float s = 0.f, accum = 0.f;
#pragma unroll
      for (int v = 0; v < 5; v++) {
        const int u = sub * 5 + v;
        const float pu = __expf(gl[v] - m);
        s += pu;
        const int cbase = (u < 10) ? (t * 100 + u * 10) : (200 + (u - 10) * 10);
        float d = 0.f;
#pragma unroll
        for (int h = 0; h < 10; h++)
          d += fmaxf(zr[cbase + h] + bias[cbase + h], 0.f) * wl[h];
        accum += pu * d;
      }
      s += __shfl_xor(s, 1);
      s += __shfl_xor(s, 2);
      accum += __shfl_xor(accum, 1);
      accum += __shfl_xor(accum, 2);
      if (sub == 0) {
        const float logit = (t ? bv[0] : bc[0]) + accum / s;
        out[(size_t)t * BROWS + rowbase + p * 32 + r] =
            1.f / (1.f + __expf(-logit));
      }
    }
  }
}

extern "C" void kernel_launch(void* const* d_in, const int* in_sizes, int n_in,
                              void* d_out, int out_size, void* d_ws, size_t ws_size,
                              hipStream_t stream) {
  const float* x = (const float*)d_in[0];
  const float* Ws = (const float*)d_in[3];
  const float* bs = (const float*)d_in[4];
  const float* Wt = (const float*)d_in[5];
  const float* bt = (const float*)d_in[6];
  const float* Wg = (const float*)d_in[7];
  const float* bg = (const float*)d_in[8];
  const float* Wc = (const float*)d_in[9];
  const float* bc = (const float*)d_in[10];
  const float* Wv = (const float*)d_in[11];
  const float* bv = (const float*)d_in[12];
  unsigned short* Wpack = (unsigned short*)d_ws;
  float* bias = (float*)((char*)d_ws + (size_t)NCOLP * 1024 * 2);
  float* out = (float*)d_out;

  hipLaunchKernelGGL(ple_prep, dim3(NCOLP), dim3(256), 0, stream, Ws, bs, Wt, bt,
                     Wg, bg, Wpack, bias);
  hipLaunchKernelGGL(ple_main, dim3(BROWS / 64), dim3(256), 0, stream, x, Wpack,
                     bias, Wc, bc, Wv, bv, out);
}